// Round 2
// baseline (418.160 us; speedup 1.0000x reference)
//
#include <hip/hip_runtime.h>
#include <hip/hip_bf16.h>
#include <math.h>

// Problem constants
#define Bn  2
#define Nn  512
#define Dn  128
#define FHn 512

typedef __hip_bfloat16 bf16;

__device__ __forceinline__ float cvt(float x) { return x; }
__device__ __forceinline__ float cvt(bf16 x) { return __bfloat162float(x); }
__device__ __forceinline__ float sigmoidf_(float x) { return 1.0f / (1.0f + expf(-x)); }

// ---------------------------------------------------------------------------
// Workspace layout (float offsets). S = one (B,N,D) f32 slab.
#define S_ 131072
#define WS_RN   (0 * S_)
#define WS_CN   (1 * S_)   // reused: xb
#define WS_Q    (2 * S_)   // reused: op (FFN out)
#define WS_KR   (3 * S_)   // reused: G
#define WS_V    (4 * S_)   // reused: mh
#define WS_EK   (5 * S_)
#define WS_EKV  (6 * S_)
#define WS_EAB  (7 * S_)   // (B,N,N) f32 = 4 slabs
#define WS_PRE  (11 * S_)  // 1040 floats
#define WS_FLAG (11 * S_ + 1040)
// total = 11*131072 + 1041 floats ~= 5.77 MB

// pre[] layout
#define P_W1   0
#define P_B1   128
#define P_A1   256
#define P_AB1  384
#define P_UD   512
#define P_VD   640
#define P_UA   768
#define P_VA   896
#define P_SC   1024  // cds, cdt, cas, cat, gate_b, outlin_b, alpha

// ---------------------------------------------------------------------------
// Detect input dtype from alpha (== 1.0 exactly).
// bf16: bytes[0:2] = 0x3F80.  f32: bytes[0:2] = 0x0000 (low half of 0x3F800000).
__global__ void k_detect(const void* alpha, int* flag) {
    if (threadIdx.x == 0) {
        const unsigned short* p = (const unsigned short*)alpha;
        flag[0] = (p[0] == 0x3F80) ? 1 : 0;
    }
}

// ---------------------------------------------------------------------------
// k_pre: fold dist_w2/ang_w2 through outlin_w and gate_w.
template <typename T>
__device__ void pre_body(const void* dw1v, const void* db1v, const void* dw2v, const void* db2v,
                         const void* aw1v, const void* ab1v, const void* aw2v, const void* ab2v,
                         const void* gwv, const void* gbv, const void* owv, const void* obv,
                         const void* alphav, float* pre) {
    const T* dw1 = (const T*)dw1v; const T* db1 = (const T*)db1v;
    const T* dw2 = (const T*)dw2v; const T* db2 = (const T*)db2v;
    const T* aw1 = (const T*)aw1v; const T* ab1 = (const T*)ab1v;
    const T* aw2 = (const T*)aw2v; const T* ab2 = (const T*)ab2v;
    const T* gw = (const T*)gwv;   const T* gb = (const T*)gbv;
    const T* ow = (const T*)owv;   const T* ob = (const T*)obv;
    const T* alpha = (const T*)alphav;
    int k = threadIdx.x;  // 0..127
    float ud = 0.f, vd = 0.f, ua = 0.f, va = 0.f;
    for (int d = 0; d < Dn; ++d) {
        float w2 = cvt(dw2[k * Dn + d]);
        float a2 = cvt(aw2[k * Dn + d]);
        float o = cvt(ow[d]);
        ud += w2 * o;
        vd += w2 * cvt(gw[d]);
        ua += a2 * o;
        va += a2 * cvt(gw[Dn + d]);
    }
    pre[P_W1 + k]  = cvt(dw1[k]);
    pre[P_B1 + k]  = cvt(db1[k]);
    pre[P_A1 + k]  = cvt(aw1[k]);
    pre[P_AB1 + k] = cvt(ab1[k]);
    pre[P_UD + k] = ud;
    pre[P_VD + k] = vd;
    pre[P_UA + k] = ua;
    pre[P_VA + k] = va;
    if (k == 0) {
        float cds = 0.f, cdt = 0.f, cas = 0.f, cat = 0.f;
        for (int d = 0; d < Dn; ++d) {
            float o = cvt(ow[d]);
            cds += cvt(db2[d]) * o;
            cdt += cvt(db2[d]) * cvt(gw[d]);
            cas += cvt(ab2[d]) * o;
            cat += cvt(ab2[d]) * cvt(gw[Dn + d]);
        }
        pre[P_SC + 0] = cds;
        pre[P_SC + 1] = cdt;
        pre[P_SC + 2] = cas;
        pre[P_SC + 3] = cat;
        pre[P_SC + 4] = cvt(gb[0]);
        pre[P_SC + 5] = cvt(ob[0]);
        pre[P_SC + 6] = cvt(alpha[0]);
    }
}

__global__ void k_pre(const void* dw1, const void* db1, const void* dw2, const void* db2,
                      const void* aw1, const void* ab1, const void* aw2, const void* ab2,
                      const void* gw, const void* gb, const void* ow, const void* ob,
                      const void* alpha, float* pre, const int* flag) {
    if (flag[0]) pre_body<bf16>(dw1, db1, dw2, db2, aw1, ab1, aw2, ab2, gw, gb, ow, ob, alpha, pre);
    else         pre_body<float>(dw1, db1, dw2, db2, aw1, ab1, aw2, ab2, gw, gb, ow, ob, alpha, pre);
}

// ---------------------------------------------------------------------------
// Instance norm over tokens for row_emb -> rn and col_emb -> cn.
// grid = 2*B blocks, 1024 threads (8 grp x 128 d)
template <typename T>
__device__ void norm_in_body(const void* rowv, const void* colv,
                             const void* n1wv, const void* n1bv,
                             const void* n2wv, const void* n2bv,
                             float* rn, float* cn) {
    int which = blockIdx.x >> 1;
    int b = blockIdx.x & 1;
    const T* src = which ? (const T*)colv : (const T*)rowv;
    const T* w = which ? (const T*)n2wv : (const T*)n1wv;
    const T* bb = which ? (const T*)n2bv : (const T*)n1bv;
    float* dst = which ? cn : rn;
    int d = threadIdx.x & 127, g = threadIdx.x >> 7;
    __shared__ float rs[8][128], rss[8][128];
    const T* base = src + (size_t)b * Nn * Dn;
    float s = 0.f, ss = 0.f;
    for (int n = g; n < Nn; n += 8) {
        float x = cvt(base[n * Dn + d]);
        s += x; ss += x * x;
    }
    rs[g][d] = s; rss[g][d] = ss;
    __syncthreads();
    if (g < 4) { rs[g][d] += rs[g+4][d]; rss[g][d] += rss[g+4][d]; } __syncthreads();
    if (g < 2) { rs[g][d] += rs[g+2][d]; rss[g][d] += rss[g+2][d]; } __syncthreads();
    if (g == 0) { rs[0][d] += rs[1][d]; rss[0][d] += rss[1][d]; } __syncthreads();
    float m = rs[0][d] * (1.f / Nn);
    float v = fmaxf(rss[0][d] * (1.f / Nn) - m * m, 0.f);
    float rstd = rsqrtf(v + 1e-5f);
    float sw = cvt(w[d]), sb = cvt(bb[d]);
    float* obase = dst + (size_t)b * Nn * Dn;
    for (int n = g; n < Nn; n += 8) {
        float x = cvt(base[n * Dn + d]);
        obase[n * Dn + d] = (x - m) * rstd * sw + sb;
    }
}

__global__ void k_norm_in(const void* row, const void* col,
                          const void* n1w, const void* n1b,
                          const void* n2w, const void* n2b,
                          float* rn, float* cn, const int* flag) {
    if (flag[0]) norm_in_body<bf16>(row, col, n1w, n1b, n2w, n2b, rn, cn);
    else         norm_in_body<float>(row, col, n1w, n1b, n2w, n2b, rn, cn);
}

// ---------------------------------------------------------------------------
// Q = sigmoid(rn@qw+qb), Kraw = cn@kw+kb, V = cn@vw+vb. 4 rows/block, 128 thr.
template <typename T>
__device__ void qkv_body(const float* __restrict__ rn, const float* __restrict__ cn,
                         const void* qwv, const void* qbv, const void* kwv, const void* kbv,
                         const void* vwv, const void* vbv,
                         float* Q, float* Kraw, float* V) {
    const T* qw = (const T*)qwv; const T* qb = (const T*)qbv;
    const T* kw = (const T*)kwv; const T* kb = (const T*)kbv;
    const T* vw = (const T*)vwv; const T* vb = (const T*)vbv;
    int h = threadIdx.x;
    int r0 = blockIdx.x * 4;
    __shared__ float lr[4][Dn], lc[4][Dn];
    for (int r = 0; r < 4; ++r) {
        lr[r][h] = rn[(r0 + r) * Dn + h];
        lc[r][h] = cn[(r0 + r) * Dn + h];
    }
    __syncthreads();
    float q[4] = {0,0,0,0}, kk[4] = {0,0,0,0}, vv[4] = {0,0,0,0};
    for (int k = 0; k < Dn; ++k) {
        float wq = cvt(qw[k * Dn + h]);
        float wk = cvt(kw[k * Dn + h]);
        float wv = cvt(vw[k * Dn + h]);
#pragma unroll
        for (int r = 0; r < 4; ++r) {
            q[r] += lr[r][k] * wq;
            kk[r] += lc[r][k] * wk;
            vv[r] += lc[r][k] * wv;
        }
    }
    float bq = cvt(qb[h]), bk = cvt(kb[h]), bv = cvt(vb[h]);
    for (int r = 0; r < 4; ++r) {
        Q[(r0 + r) * Dn + h] = sigmoidf_(q[r] + bq);
        Kraw[(r0 + r) * Dn + h] = kk[r] + bk;
        V[(r0 + r) * Dn + h] = vv[r] + bv;
    }
}

__global__ void k_qkv(const float* rn, const float* cn,
                      const void* qw, const void* qb, const void* kw, const void* kb,
                      const void* vw, const void* vb,
                      float* Q, float* Kraw, float* V, const int* flag) {
    if (flag[0]) qkv_body<bf16>(rn, cn, qw, qb, kw, kb, vw, vb, Q, Kraw, V);
    else         qkv_body<float>(rn, cn, qw, qb, kw, kb, vw, vb, Q, Kraw, V);
}

// ---------------------------------------------------------------------------
// K-softmax over tokens (axis=1), then eK = exp(softmax), eKV = eK*V.
// grid = B, 1024 threads (8 grp x 128 h). All-f32, no dtype branch.
__global__ void k_ksm(const float* Kraw, const float* V, float* eK, float* eKV) {
    int b = blockIdx.x;
    int h = threadIdx.x & 127, g = threadIdx.x >> 7;
    __shared__ float red[8][128];
    const float* kb = Kraw + (size_t)b * Nn * Dn;
    const float* vb = V + (size_t)b * Nn * Dn;
    float* ekb = eK + (size_t)b * Nn * Dn;
    float* evb = eKV + (size_t)b * Nn * Dn;
    float mx = -1e30f;
    for (int n = g; n < Nn; n += 8) mx = fmaxf(mx, kb[n * Dn + h]);
    red[g][h] = mx; __syncthreads();
    if (g < 4) red[g][h] = fmaxf(red[g][h], red[g+4][h]); __syncthreads();
    if (g < 2) red[g][h] = fmaxf(red[g][h], red[g+2][h]); __syncthreads();
    if (g == 0) red[0][h] = fmaxf(red[0][h], red[1][h]); __syncthreads();
    mx = red[0][h];
    __syncthreads();
    float s = 0.f;
    for (int n = g; n < Nn; n += 8) s += expf(kb[n * Dn + h] - mx);
    red[g][h] = s; __syncthreads();
    if (g < 4) red[g][h] += red[g+4][h]; __syncthreads();
    if (g < 2) red[g][h] += red[g+2][h]; __syncthreads();
    if (g == 0) red[0][h] += red[1][h]; __syncthreads();
    float rsum = 1.f / red[0][h];
    for (int n = g; n < Nn; n += 8) {
        float ksm = expf(kb[n * Dn + h] - mx) * rsum;
        float e = expf(ksm);
        ekb[n * Dn + h] = e;
        evb[n * Dn + h] = e * vb[n * Dn + h];
    }
}

// ---------------------------------------------------------------------------
// adapt_bias row -> softmax over j -> exp -> eab.  grid = B*N, 256 threads.
template <typename T>
__device__ void eab_body(const void* costv, const void* coordsv,
                         const float* __restrict__ pre, float* __restrict__ eab) {
    const T* cost = (const T*)costv;
    const T* coords = (const T*)coordsv;
    int bi = blockIdx.x;
    int b = bi >> 9, i = bi & 511;
    int t = threadIdx.x;
    __shared__ float abv[Nn];
    __shared__ float red[256];
    const float* pw1 = pre + P_W1;
    const float* pb1 = pre + P_B1;
    const float* pa1 = pre + P_A1;
    const float* pab = pre + P_AB1;
    const float* pud = pre + P_UD;
    const float* pvd = pre + P_VD;
    const float* pua = pre + P_UA;
    const float* pva = pre + P_VA;
    float cds = pre[P_SC+0], cdt = pre[P_SC+1], cas = pre[P_SC+2], cat = pre[P_SC+3];
    float gbias = pre[P_SC+4], obias = pre[P_SC+5], alpha = pre[P_SC+6];
    float cix = cvt(coords[((size_t)b * Nn + i) * 2 + 0]);
    float ciy = cvt(coords[((size_t)b * Nn + i) * 2 + 1]);
    const T* crow = cost + (size_t)b * Nn * Nn + (size_t)i * Nn;

    for (int j = t; j < Nn; j += 256) {
        float c = cvt(crow[j]);
        float dx = cix - cvt(coords[((size_t)b * Nn + j) * 2 + 0]);
        float dy = ciy - cvt(coords[((size_t)b * Nn + j) * 2 + 1]);
        // np.arctan2(0,0) == 0; guard against any non-IEEE fast-path NaN
        float ang = (dx == 0.f && dy == 0.f) ? 0.f : atan2f(dy, dx);
        float sd = cds, td = cdt, sa = cas, ta = cat;
#pragma unroll 4
        for (int k = 0; k < Dn; ++k) {
            float r = fmaxf(fmaf(c, pw1[k], pb1[k]), 0.f);
            sd = fmaf(r, pud[k], sd);
            td = fmaf(r, pvd[k], td);
            float ra = fmaxf(fmaf(ang, pa1[k], pab[k]), 0.f);
            sa = fmaf(ra, pua[k], sa);
            ta = fmaf(ra, pva[k], ta);
        }
        float gv = sigmoidf_(td + ta + gbias);
        abv[j] = alpha * (gv * sd + (1.f - gv) * sa + obias);
    }
    __syncthreads();
    float m = fmaxf(abv[t], abv[t + 256]);
    red[t] = m; __syncthreads();
    for (int s = 128; s > 0; s >>= 1) {
        if (t < s) red[t] = fmaxf(red[t], red[t + s]);
        __syncthreads();
    }
    m = red[0];
    __syncthreads();
    float e0 = expf(abv[t] - m), e1 = expf(abv[t + 256] - m);
    red[t] = e0 + e1; __syncthreads();
    for (int s = 128; s > 0; s >>= 1) {
        if (t < s) red[t] += red[t + s];
        __syncthreads();
    }
    float rsum = 1.f / red[0];
    float* orow = eab + (size_t)bi * Nn;
    orow[t] = expf(e0 * rsum);
    orow[t + 256] = expf(e1 * rsum);
}

__global__ void k_eab(const void* cost, const void* coords,
                      const float* pre, float* eab, const int* flag) {
    if (flag[0]) eab_body<bf16>(cost, coords, pre, eab);
    else         eab_body<float>(cost, coords, pre, eab);
}

// ---------------------------------------------------------------------------
// num/den einsums + G = Q*num/den. 4 rows/block, 128 threads. All-f32.
__global__ void k_numden(const float* __restrict__ eab, const float* __restrict__ eK,
                         const float* __restrict__ eKV, const float* __restrict__ Q,
                         float* __restrict__ G) {
    int h = threadIdx.x;
    int r0 = blockIdx.x * 4;
    int b = r0 >> 9;
    __shared__ float ab[4][Nn];
    for (int r = 0; r < 4; ++r)
        for (int j = h; j < Nn; j += 128)
            ab[r][j] = eab[(size_t)(r0 + r) * Nn + j];
    __syncthreads();
    const float* ekb = eK + (size_t)b * Nn * Dn;
    const float* evb = eKV + (size_t)b * Nn * Dn;
    float num[4] = {0,0,0,0}, den[4] = {0,0,0,0};
    for (int j = 0; j < Nn; ++j) {
        float ek = ekb[j * Dn + h];
        float ev = evb[j * Dn + h];
#pragma unroll
        for (int r = 0; r < 4; ++r) {
            num[r] += ab[r][j] * ev;
            den[r] += ab[r][j] * ek;
        }
    }
    for (int r = 0; r < 4; ++r) {
        int row = r0 + r;
        G[row * Dn + h] = Q[row * Dn + h] * num[r] / den[r];
    }
}

// ---------------------------------------------------------------------------
// Yt = G@pw+pb then mh_raw = Yt@mw+mb. 4 rows/block, 128 threads.
template <typename T>
__device__ void pmhc_body(const float* __restrict__ G, const void* pwv, const void* pbv,
                          const void* mwv, const void* mbv, float* mh_raw) {
    const T* pw = (const T*)pwv; const T* pb = (const T*)pbv;
    const T* mw = (const T*)mwv; const T* mb = (const T*)mbv;
    int h = threadIdx.x;
    int r0 = blockIdx.x * 4;
    __shared__ float gl[4][Dn];
    __shared__ float yl[4][Dn];
    for (int r = 0; r < 4; ++r) gl[r][h] = G[(r0 + r) * Dn + h];
    __syncthreads();
    float acc[4] = {0,0,0,0};
    for (int k = 0; k < Dn; ++k) {
        float w = cvt(pw[k * Dn + h]);
#pragma unroll
        for (int r = 0; r < 4; ++r) acc[r] += gl[r][k] * w;
    }
    float bp = cvt(pb[h]);
    for (int r = 0; r < 4; ++r) yl[r][h] = acc[r] + bp;
    __syncthreads();
    float a2[4] = {0,0,0,0};
    for (int k = 0; k < Dn; ++k) {
        float w = cvt(mw[k * Dn + h]);
#pragma unroll
        for (int r = 0; r < 4; ++r) a2[r] += yl[r][k] * w;
    }
    float bm = cvt(mb[h]);
    for (int r = 0; r < 4; ++r) mh_raw[(r0 + r) * Dn + h] = a2[r] + bm;
}

__global__ void k_pmhc(const float* G, const void* pw, const void* pb,
                       const void* mw, const void* mb, float* mh_raw, const int* flag) {
    if (flag[0]) pmhc_body<bf16>(G, pw, pb, mw, mb, mh_raw);
    else         pmhc_body<float>(G, pw, pb, mw, mb, mh_raw);
}

// ---------------------------------------------------------------------------
// mh = inorm(mh_raw, n3); x = inorm(rn + mh, fn1) -> xbuf. grid=B, 1024 thr.
template <typename T>
__device__ void norm_mid_body(const float* mh_raw, const float* rn,
                              const void* n3wv, const void* n3bv,
                              const void* f1wv, const void* f1bv, float* xbuf) {
    const T* n3w = (const T*)n3wv; const T* n3b = (const T*)n3bv;
    const T* f1w = (const T*)f1wv; const T* f1b = (const T*)f1bv;
    int b = blockIdx.x;
    int d = threadIdx.x & 127, g = threadIdx.x >> 7;
    __shared__ float rs[8][128], rss[8][128];
    const float* src = mh_raw + (size_t)b * Nn * Dn;
    const float* rnb = rn + (size_t)b * Nn * Dn;
    float* xb = xbuf + (size_t)b * Nn * Dn;
    float s = 0.f, ss = 0.f;
    for (int n = g; n < Nn; n += 8) { float x = src[n * Dn + d]; s += x; ss += x * x; }
    rs[g][d] = s; rss[g][d] = ss; __syncthreads();
    if (g < 4) { rs[g][d] += rs[g+4][d]; rss[g][d] += rss[g+4][d]; } __syncthreads();
    if (g < 2) { rs[g][d] += rs[g+2][d]; rss[g][d] += rss[g+2][d]; } __syncthreads();
    if (g == 0) { rs[0][d] += rs[1][d]; rss[0][d] += rss[1][d]; } __syncthreads();
    float m1 = rs[0][d] * (1.f / Nn);
    float v1 = fmaxf(rss[0][d] * (1.f / Nn) - m1 * m1, 0.f);
    float r1 = rsqrtf(v1 + 1e-5f);
    __syncthreads();
    float w3 = cvt(n3w[d]), b3 = cvt(n3b[d]);
    s = 0.f; ss = 0.f;
    for (int n = g; n < Nn; n += 8) {
        float t = rnb[n * Dn + d] + (src[n * Dn + d] - m1) * r1 * w3 + b3;
        xb[n * Dn + d] = t; s += t; ss += t * t;
    }
    rs[g][d] = s; rss[g][d] = ss; __syncthreads();
    if (g < 4) { rs[g][d] += rs[g+4][d]; rss[g][d] += rss[g+4][d]; } __syncthreads();
    if (g < 2) { rs[g][d] += rs[g+2][d]; rss[g][d] += rss[g+2][d]; } __syncthreads();
    if (g == 0) { rs[0][d] += rs[1][d]; rss[0][d] += rss[1][d]; } __syncthreads();
    float m2 = rs[0][d] * (1.f / Nn);
    float v2 = fmaxf(rss[0][d] * (1.f / Nn) - m2 * m2, 0.f);
    float r2 = rsqrtf(v2 + 1e-5f);
    float wf = cvt(f1w[d]), bf = cvt(f1b[d]);
    for (int n = g; n < Nn; n += 8) {
        float t = xb[n * Dn + d];
        xb[n * Dn + d] = (t - m2) * r2 * wf + bf;
    }
}

__global__ void k_norm_mid(const float* mh_raw, const float* rn,
                           const void* n3w, const void* n3b,
                           const void* f1w, const void* f1b, float* xbuf, const int* flag) {
    if (flag[0]) norm_mid_body<bf16>(mh_raw, rn, n3w, n3b, f1w, f1b, xbuf);
    else         norm_mid_body<float>(mh_raw, rn, n3w, n3b, f1w, f1b, xbuf);
}

// ---------------------------------------------------------------------------
// FFN: hidden in LDS, outpre = x + ff. 4 rows/block, 512 threads.
template <typename T>
__device__ void ffn_body(const float* __restrict__ xbuf, const void* w1v, const void* b1v,
                         const void* w2v, const void* b2v, float* outpre) {
    const T* w1 = (const T*)w1v; const T* bb1p = (const T*)b1v;
    const T* w2 = (const T*)w2v; const T* bb2p = (const T*)b2v;
    int t = threadIdx.x;
    int r0 = blockIdx.x * 4;
    __shared__ float xl[4][Dn];
    __shared__ float hl[4][FHn];
    { int r = t >> 7, d = t & 127; xl[r][d] = xbuf[(r0 + r) * Dn + d]; }
    __syncthreads();
    float acc[4] = {0,0,0,0};
    for (int k = 0; k < Dn; ++k) {
        float w = cvt(w1[k * FHn + t]);
#pragma unroll
        for (int r = 0; r < 4; ++r) acc[r] += xl[r][k] * w;
    }
    float bb1 = cvt(bb1p[t]);
    for (int r = 0; r < 4; ++r) hl[r][t] = fmaxf(acc[r] + bb1, 0.f);
    __syncthreads();
    if (t < Dn) {
        float a2[4] = {0,0,0,0};
        for (int k = 0; k < FHn; ++k) {
            float w = cvt(w2[k * Dn + t]);
#pragma unroll
            for (int r = 0; r < 4; ++r) a2[r] += hl[r][k] * w;
        }
        float bb2 = cvt(bb2p[t]);
        for (int r = 0; r < 4; ++r)
            outpre[(r0 + r) * Dn + t] = xl[r][t] + a2[r] + bb2;
    }
}

__global__ void k_ffn(const float* xbuf, const void* w1, const void* b1,
                      const void* w2, const void* b2, float* outpre, const int* flag) {
    if (flag[0]) ffn_body<bf16>(xbuf, w1, b1, w2, b2, outpre);
    else         ffn_body<float>(xbuf, w1, b1, w2, b2, outpre);
}

// ---------------------------------------------------------------------------
// out = inorm(outpre, fn2) -> output dtype = input dtype. grid=B, 1024 thr.
template <typename T>
__device__ void norm_out_body(const float* outpre, const void* f2wv, const void* f2bv,
                              void* outv) {
    const T* f2w = (const T*)f2wv; const T* f2b = (const T*)f2bv;
    T* out = (T*)outv;
    int b = blockIdx.x;
    int d = threadIdx.x & 127, g = threadIdx.x >> 7;
    __shared__ float rs[8][128], rss[8][128];
    const float* src = outpre + (size_t)b * Nn * Dn;
    T* ob = out + (size_t)b * Nn * Dn;
    float s = 0.f, ss = 0.f;
    for (int n = g; n < Nn; n += 8) { float x = src[n * Dn + d]; s += x; ss += x * x; }
    rs[g][d] = s; rss[g][d] = ss; __syncthreads();
    if (g < 4) { rs[g][d] += rs[g+4][d]; rss[g][d] += rss[g+4][d]; } __syncthreads();
    if (g < 2) { rs[g][d] += rs[g+2][d]; rss[g][d] += rss[g+2][d]; } __syncthreads();
    if (g == 0) { rs[0][d] += rs[1][d]; rss[0][d] += rss[1][d]; } __syncthreads();
    float m = rs[0][d] * (1.f / Nn);
    float v = fmaxf(rss[0][d] * (1.f / Nn) - m * m, 0.f);
    float rstd = rsqrtf(v + 1e-5f);
    float sw = cvt(f2w[d]), sb = cvt(f2b[d]);
    for (int n = g; n < Nn; n += 8) {
        float x = src[n * Dn + d];
        out[(size_t)b * Nn * Dn + n * Dn + d] = (T)((x - m) * rstd * sw + sb);
    }
    (void)ob;
}

__global__ void k_norm_out(const float* outpre, const void* f2w, const void* f2b,
                           void* out, const int* flag) {
    if (flag[0]) norm_out_body<bf16>(outpre, f2w, f2b, out);
    else         norm_out_body<float>(outpre, f2w, f2b, out);
}

// ---------------------------------------------------------------------------
extern "C" void kernel_launch(void* const* d_in, const int* in_sizes, int n_in,
                              void* d_out, int out_size, void* d_ws, size_t ws_size,
                              hipStream_t stream) {
    const void* row_emb  = d_in[0];
    const void* col_emb  = d_in[1];
    const void* cost_mat = d_in[2];
    const void* coords   = d_in[3];
    const void* alpha    = d_in[4];
    const void* n1w = d_in[5];  const void* n1b = d_in[6];
    const void* n2w = d_in[7];  const void* n2b = d_in[8];
    const void* n3w = d_in[9];  const void* n3b = d_in[10];
    const void* f1w = d_in[11]; const void* f1b = d_in[12];
    const void* f2w = d_in[13]; const void* f2b = d_in[14];
    const void* qw = d_in[15];  const void* qb = d_in[16];
    const void* kw = d_in[17];  const void* kb = d_in[18];
    const void* vw = d_in[19];  const void* vb = d_in[20];
    const void* pw = d_in[21];  const void* pb = d_in[22];
    const void* mw = d_in[23];  const void* mb = d_in[24];
    const void* dw1 = d_in[25]; const void* db1 = d_in[26];
    const void* dw2 = d_in[27]; const void* db2 = d_in[28];
    const void* aw1 = d_in[29]; const void* ab1 = d_in[30];
    const void* aw2 = d_in[31]; const void* ab2 = d_in[32];
    const void* gw = d_in[33];  const void* gb = d_in[34];
    const void* ow = d_in[35];  const void* ob = d_in[36];
    const void* ffw1 = d_in[37]; const void* ffb1 = d_in[38];
    const void* ffw2 = d_in[39]; const void* ffb2 = d_in[40];

    float* ws = (float*)d_ws;
    float* rn   = ws + WS_RN;
    float* cn   = ws + WS_CN;   // later reused as xb
    float* Q    = ws + WS_Q;    // later reused as op
    float* Kraw = ws + WS_KR;   // later reused as G
    float* V    = ws + WS_V;    // later reused as mh
    float* eK   = ws + WS_EK;
    float* eKV  = ws + WS_EKV;
    float* eab  = ws + WS_EAB;
    float* pre  = ws + WS_PRE;
    int*   flag = (int*)(ws + WS_FLAG);

    float* G  = Kraw;
    float* mh = V;
    float* xb = cn;
    float* op = Q;

    k_detect<<<1, 64, 0, stream>>>(alpha, flag);
    k_pre<<<1, 128, 0, stream>>>(dw1, db1, dw2, db2, aw1, ab1, aw2, ab2,
                                 gw, gb, ow, ob, alpha, pre, flag);
    k_norm_in<<<2 * Bn, 1024, 0, stream>>>(row_emb, col_emb, n1w, n1b, n2w, n2b, rn, cn, flag);
    k_qkv<<<(Bn * Nn) / 4, 128, 0, stream>>>(rn, cn, qw, qb, kw, kb, vw, vb, Q, Kraw, V, flag);
    k_ksm<<<Bn, 1024, 0, stream>>>(Kraw, V, eK, eKV);
    k_eab<<<Bn * Nn, 256, 0, stream>>>(cost_mat, coords, pre, eab, flag);
    k_numden<<<(Bn * Nn) / 4, 128, 0, stream>>>(eab, eK, eKV, Q, G);
    k_pmhc<<<(Bn * Nn) / 4, 128, 0, stream>>>(G, pw, pb, mw, mb, mh, flag);
    k_norm_mid<<<Bn, 1024, 0, stream>>>(mh, rn, n3w, n3b, f1w, f1b, xb, flag);
    k_ffn<<<(Bn * Nn) / 4, 512, 0, stream>>>(xb, ffw1, ffb1, ffw2, ffb2, op, flag);
    k_norm_out<<<Bn, 1024, 0, stream>>>(op, f2w, f2b, d_out, flag);
}

// Round 3
// 304.315 us; speedup vs baseline: 1.3741x; 1.3741x over previous
//
#include <hip/hip_runtime.h>
#include <hip/hip_bf16.h>
#include <math.h>

// Problem constants
#define Bn  2
#define Nn  512
#define Dn  128
#define FHn 512
#define BND (Bn*Nn*Dn)   // 131072

typedef __hip_bfloat16 bf16;

__device__ __forceinline__ float cvt(float x) { return x; }
__device__ __forceinline__ float cvt(bf16 x) { return __bfloat162float(x); }
__device__ __forceinline__ float sigmoidf_(float x) { return 1.0f / (1.0f + expf(-x)); }
// dtype flag: alpha == 1.0 exactly. bf16 stores 0x3F80 in bytes[0:2); f32 stores 0x0000.
__device__ __forceinline__ bool is_bf16(const void* alpha) {
    return ((const unsigned short*)alpha)[0] == 0x3F80;
}

// ---------------------------------------------------------------------------
// Workspace layout (float offsets). S = one (B,N,D) f32 slab = 131072 floats.
#define S_ 131072
#define WS_Q    (0 * S_)   // reused: t (build_x output)
#define WS_K    (1 * S_)   // reused: G
#define WS_V    (2 * S_)   // reused: mh_raw
#define WS_EK   (3 * S_)   // reused: outpre
#define WS_EKV  (4 * S_)
#define WS_EAB  (5 * S_)   // (B,N,N) f32 = 4 slabs
#define WS_ST   (9 * S_)   // stats + pre region

// stats region (float offsets inside WS_ST)
#define ST_IN_SC   0      // 512: [which*256 + b*128 + d]
#define ST_IN_SH   512
#define ST_KMX     1024   // 256: [b*128 + h]
#define ST_KRS     1280
#define ST_MH_SC   1536
#define ST_MH_SH   1792
#define ST_X_SC    2048
#define ST_X_SH    2304
#define ST_O_SC    2560
#define ST_O_SH    2816
#define ST_PRE     3072   // 1040 floats
// total stats = 4112 floats; ws total = 9*S_ + 4112 ~= 4.73 MB

// pre[] layout (relative to ST_PRE)
#define P_W1   0
#define P_B1   128
#define P_A1   256
#define P_AB1  384
#define P_UD   512
#define P_VD   640
#define P_UA   768
#define P_VA   896
#define P_SC   1024  // cds, cdt, cas, cat, gate_b, outlin_b, alpha

// ---------------------------------------------------------------------------
// k_head: blocks 0..127 = input instance-norm stats (512 columns, 4/block,
// wave-per-column); block 128 = pre-fold of the DistAngleFusion MLPs.
template <typename T>
__device__ void head_stats(const void* rowv, const void* colv,
                           const void* n1wv, const void* n1bv,
                           const void* n2wv, const void* n2bv, float* st) {
    int wave = threadIdx.x >> 6, lane = threadIdx.x & 63;
    int cid = blockIdx.x * 4 + wave;          // 0..511
    int which = cid >> 8, rem = cid & 255;
    int b = rem >> 7, d = rem & 127;
    const T* src = (which ? (const T*)colv : (const T*)rowv) + (size_t)b * Nn * Dn + d;
    float s = 0.f, ss = 0.f;
#pragma unroll
    for (int k = 0; k < 8; ++k) {
        float x = cvt(src[(size_t)(lane + 64 * k) * Dn]);
        s += x; ss += x * x;
    }
#pragma unroll
    for (int off = 32; off > 0; off >>= 1) {
        s += __shfl_down(s, off);
        ss += __shfl_down(ss, off);
    }
    if (lane == 0) {
        float m = s * (1.f / Nn);
        float v = fmaxf(ss * (1.f / Nn) - m * m, 0.f);
        float rstd = rsqrtf(v + 1e-5f);
        const T* w = which ? (const T*)n2wv : (const T*)n1wv;
        const T* bb = which ? (const T*)n2bv : (const T*)n1bv;
        float sc = rstd * cvt(w[d]);
        st[ST_IN_SC + cid] = sc;
        st[ST_IN_SH + cid] = cvt(bb[d]) - m * sc;
    }
}

template <typename T>
__device__ void pre_fold(const void* dw1v, const void* db1v, const void* dw2v, const void* db2v,
                         const void* aw1v, const void* ab1v, const void* aw2v, const void* ab2v,
                         const void* gwv, const void* gbv, const void* owv, const void* obv,
                         const void* alphav, float* pre) {
    const T* dw1 = (const T*)dw1v; const T* db1 = (const T*)db1v;
    const T* dw2 = (const T*)dw2v; const T* db2 = (const T*)db2v;
    const T* aw1 = (const T*)aw1v; const T* ab1 = (const T*)ab1v;
    const T* aw2 = (const T*)aw2v; const T* ab2 = (const T*)ab2v;
    const T* gw = (const T*)gwv;   const T* gb = (const T*)gbv;
    const T* ow = (const T*)owv;   const T* ob = (const T*)obv;
    const T* alpha = (const T*)alphav;
    int k = threadIdx.x;
    if (k >= 128) return;
    float ud = 0.f, vd = 0.f, ua = 0.f, va = 0.f;
    for (int d = 0; d < Dn; ++d) {
        float w2 = cvt(dw2[k * Dn + d]);
        float a2 = cvt(aw2[k * Dn + d]);
        float o = cvt(ow[d]);
        ud += w2 * o;
        vd += w2 * cvt(gw[d]);
        ua += a2 * o;
        va += a2 * cvt(gw[Dn + d]);
    }
    pre[P_W1 + k]  = cvt(dw1[k]);
    pre[P_B1 + k]  = cvt(db1[k]);
    pre[P_A1 + k]  = cvt(aw1[k]);
    pre[P_AB1 + k] = cvt(ab1[k]);
    pre[P_UD + k] = ud;
    pre[P_VD + k] = vd;
    pre[P_UA + k] = ua;
    pre[P_VA + k] = va;
    if (k == 0) {
        float cds = 0.f, cdt = 0.f, cas = 0.f, cat = 0.f;
        for (int d = 0; d < Dn; ++d) {
            float o = cvt(ow[d]);
            cds += cvt(db2[d]) * o;
            cdt += cvt(db2[d]) * cvt(gw[d]);
            cas += cvt(ab2[d]) * o;
            cat += cvt(ab2[d]) * cvt(gw[Dn + d]);
        }
        pre[P_SC + 0] = cds;
        pre[P_SC + 1] = cdt;
        pre[P_SC + 2] = cas;
        pre[P_SC + 3] = cat;
        pre[P_SC + 4] = cvt(gb[0]);
        pre[P_SC + 5] = cvt(ob[0]);
        pre[P_SC + 6] = cvt(alpha[0]);
    }
}

__global__ void k_head(const void* row, const void* col,
                       const void* n1w, const void* n1b, const void* n2w, const void* n2b,
                       const void* dw1, const void* db1, const void* dw2, const void* db2,
                       const void* aw1, const void* ab1, const void* aw2, const void* ab2,
                       const void* gw, const void* gb, const void* ow, const void* ob,
                       const void* alpha, float* st) {
    bool bf = is_bf16(alpha);
    if (blockIdx.x < 128) {
        if (bf) head_stats<bf16>(row, col, n1w, n1b, n2w, n2b, st);
        else    head_stats<float>(row, col, n1w, n1b, n2w, n2b, st);
    } else {
        if (bf) pre_fold<bf16>(dw1, db1, dw2, db2, aw1, ab1, aw2, ab2, gw, gb, ow, ob, alpha, st + ST_PRE);
        else    pre_fold<float>(dw1, db1, dw2, db2, aw1, ab1, aw2, ab2, gw, gb, ow, ob, alpha, st + ST_PRE);
    }
}

// ---------------------------------------------------------------------------
// k_qkv: normalize raw row/col inline via stats, then Q/Kraw/V projections.
// 4 rows/block, 128 threads.
template <typename T>
__device__ void qkv_body(const void* rowv, const void* colv, const float* __restrict__ st,
                         const void* qwv, const void* qbv, const void* kwv, const void* kbv,
                         const void* vwv, const void* vbv,
                         float* Q, float* Kraw, float* V) {
    const T* row = (const T*)rowv; const T* col = (const T*)colv;
    const T* qw = (const T*)qwv; const T* qb = (const T*)qbv;
    const T* kw = (const T*)kwv; const T* kb = (const T*)kbv;
    const T* vw = (const T*)vwv; const T* vb = (const T*)vbv;
    int h = threadIdx.x;
    int r0 = blockIdx.x * 4;
    int b = r0 >> 9;
    float scR = st[ST_IN_SC + b * 128 + h],       shR = st[ST_IN_SH + b * 128 + h];
    float scC = st[ST_IN_SC + 256 + b * 128 + h], shC = st[ST_IN_SH + 256 + b * 128 + h];
    __shared__ float lr[4][Dn], lc[4][Dn];
    for (int r = 0; r < 4; ++r) {
        lr[r][h] = cvt(row[(size_t)(r0 + r) * Dn + h]) * scR + shR;
        lc[r][h] = cvt(col[(size_t)(r0 + r) * Dn + h]) * scC + shC;
    }
    __syncthreads();
    float q[4] = {0,0,0,0}, kk[4] = {0,0,0,0}, vv[4] = {0,0,0,0};
    for (int k = 0; k < Dn; ++k) {
        float wq = cvt(qw[k * Dn + h]);
        float wk = cvt(kw[k * Dn + h]);
        float wv = cvt(vw[k * Dn + h]);
#pragma unroll
        for (int r = 0; r < 4; ++r) {
            q[r] += lr[r][k] * wq;
            kk[r] += lc[r][k] * wk;
            vv[r] += lc[r][k] * wv;
        }
    }
    float bq = cvt(qb[h]), bk = cvt(kb[h]), bv = cvt(vb[h]);
    for (int r = 0; r < 4; ++r) {
        Q[(r0 + r) * Dn + h] = sigmoidf_(q[r] + bq);
        Kraw[(r0 + r) * Dn + h] = kk[r] + bk;
        V[(r0 + r) * Dn + h] = vv[r] + bv;
    }
}

__global__ void k_qkv(const void* row, const void* col, const float* st,
                      const void* qw, const void* qb, const void* kw, const void* kb,
                      const void* vw, const void* vb,
                      float* Q, float* Kraw, float* V, const void* alpha) {
    if (is_bf16(alpha)) qkv_body<bf16>(row, col, st, qw, qb, kw, kb, vw, vb, Q, Kraw, V);
    else                qkv_body<float>(row, col, st, qw, qb, kw, kb, vw, vb, Q, Kraw, V);
}

// ---------------------------------------------------------------------------
// k_kekv: per-(b,h) K-softmax stats + fused eK/eKV write. Wave-per-column,
// grid = 64 blocks x 256 threads. All f32.
__global__ void k_kekv(const float* __restrict__ Kraw, const float* __restrict__ V,
                       float* __restrict__ eK, float* __restrict__ eKV, float* st) {
    int wave = threadIdx.x >> 6, lane = threadIdx.x & 63;
    int c = blockIdx.x * 4 + wave;   // 0..255
    int b = c >> 7, h = c & 127;
    const float* kb = Kraw + (size_t)b * Nn * Dn + h;
    const float* vb = V + (size_t)b * Nn * Dn + h;
    float* ekb = eK + (size_t)b * Nn * Dn + h;
    float* evb = eKV + (size_t)b * Nn * Dn + h;
    float x[8];
    float mx = -1e30f;
#pragma unroll
    for (int k = 0; k < 8; ++k) {
        x[k] = kb[(size_t)(lane + 64 * k) * Dn];
        mx = fmaxf(mx, x[k]);
    }
#pragma unroll
    for (int off = 32; off > 0; off >>= 1) mx = fmaxf(mx, __shfl_xor(mx, off));
    float s = 0.f;
#pragma unroll
    for (int k = 0; k < 8; ++k) s += expf(x[k] - mx);
#pragma unroll
    for (int off = 32; off > 0; off >>= 1) s += __shfl_xor(s, off);
    float rs = 1.f / s;
    if (lane == 0) { st[ST_KMX + c] = mx; st[ST_KRS + c] = rs; }
#pragma unroll
    for (int k = 0; k < 8; ++k) {
        size_t a = (size_t)(lane + 64 * k) * Dn;
        float ek = expf(expf(x[k] - mx) * rs);
        ekb[a] = ek;
        evb[a] = ek * vb[a];
    }
}

// ---------------------------------------------------------------------------
// adapt_bias row -> softmax over j -> exp -> eab.  grid = B*N, 256 threads.
template <typename T>
__device__ void eab_body(const void* costv, const void* coordsv,
                         const float* __restrict__ pre, float* __restrict__ eab) {
    const T* cost = (const T*)costv;
    const T* coords = (const T*)coordsv;
    int bi = blockIdx.x;
    int b = bi >> 9, i = bi & 511;
    int t = threadIdx.x;
    __shared__ float abv[Nn];
    __shared__ float red[256];
    const float* pw1 = pre + P_W1;
    const float* pb1 = pre + P_B1;
    const float* pa1 = pre + P_A1;
    const float* pab = pre + P_AB1;
    const float* pud = pre + P_UD;
    const float* pvd = pre + P_VD;
    const float* pua = pre + P_UA;
    const float* pva = pre + P_VA;
    float cds = pre[P_SC+0], cdt = pre[P_SC+1], cas = pre[P_SC+2], cat = pre[P_SC+3];
    float gbias = pre[P_SC+4], obias = pre[P_SC+5], alpha = pre[P_SC+6];
    float cix = cvt(coords[((size_t)b * Nn + i) * 2 + 0]);
    float ciy = cvt(coords[((size_t)b * Nn + i) * 2 + 1]);
    const T* crow = cost + (size_t)b * Nn * Nn + (size_t)i * Nn;

    for (int j = t; j < Nn; j += 256) {
        float c = cvt(crow[j]);
        float dx = cix - cvt(coords[((size_t)b * Nn + j) * 2 + 0]);
        float dy = ciy - cvt(coords[((size_t)b * Nn + j) * 2 + 1]);
        float ang = (dx == 0.f && dy == 0.f) ? 0.f : atan2f(dy, dx);
        float sd = cds, td = cdt, sa = cas, ta = cat;
#pragma unroll 4
        for (int k = 0; k < Dn; ++k) {
            float r = fmaxf(fmaf(c, pw1[k], pb1[k]), 0.f);
            sd = fmaf(r, pud[k], sd);
            td = fmaf(r, pvd[k], td);
            float ra = fmaxf(fmaf(ang, pa1[k], pab[k]), 0.f);
            sa = fmaf(ra, pua[k], sa);
            ta = fmaf(ra, pva[k], ta);
        }
        float gv = sigmoidf_(td + ta + gbias);
        abv[j] = alpha * (gv * sd + (1.f - gv) * sa + obias);
    }
    __syncthreads();
    float m = fmaxf(abv[t], abv[t + 256]);
    red[t] = m; __syncthreads();
    for (int s = 128; s > 0; s >>= 1) {
        if (t < s) red[t] = fmaxf(red[t], red[t + s]);
        __syncthreads();
    }
    m = red[0];
    __syncthreads();
    float e0 = expf(abv[t] - m), e1 = expf(abv[t + 256] - m);
    red[t] = e0 + e1; __syncthreads();
    for (int s = 128; s > 0; s >>= 1) {
        if (t < s) red[t] += red[t + s];
        __syncthreads();
    }
    float rsum = 1.f / red[0];
    float* orow = eab + (size_t)bi * Nn;
    orow[t] = expf(e0 * rsum);
    orow[t + 256] = expf(e1 * rsum);
}

__global__ void k_eab(const void* cost, const void* coords,
                      const float* pre, float* eab, const void* alpha) {
    if (is_bf16(alpha)) eab_body<bf16>(cost, coords, pre, eab);
    else                eab_body<float>(cost, coords, pre, eab);
}

// ---------------------------------------------------------------------------
// num/den einsums + G = Q*num/den. 4 rows/block, 128 threads. All-f32.
__global__ void k_numden(const float* __restrict__ eab, const float* __restrict__ eK,
                         const float* __restrict__ eKV, const float* __restrict__ Q,
                         float* __restrict__ G) {
    int h = threadIdx.x;
    int r0 = blockIdx.x * 4;
    int b = r0 >> 9;
    __shared__ float ab[4][Nn];
    for (int r = 0; r < 4; ++r)
        for (int j = h; j < Nn; j += 128)
            ab[r][j] = eab[(size_t)(r0 + r) * Nn + j];
    __syncthreads();
    const float* ekb = eK + (size_t)b * Nn * Dn;
    const float* evb = eKV + (size_t)b * Nn * Dn;
    float num[4] = {0,0,0,0}, den[4] = {0,0,0,0};
    for (int j = 0; j < Nn; ++j) {
        float ek = ekb[j * Dn + h];
        float ev = evb[j * Dn + h];
#pragma unroll
        for (int r = 0; r < 4; ++r) {
            num[r] += ab[r][j] * ev;
            den[r] += ab[r][j] * ek;
        }
    }
    for (int r = 0; r < 4; ++r) {
        int row = r0 + r;
        G[row * Dn + h] = Q[row * Dn + h] * num[r] / den[r];
    }
}

// ---------------------------------------------------------------------------
// Yt = G@pw+pb then mh_raw = Yt@mw+mb. 4 rows/block, 128 threads.
template <typename T>
__device__ void pmhc_body(const float* __restrict__ G, const void* pwv, const void* pbv,
                          const void* mwv, const void* mbv, float* mh_raw) {
    const T* pw = (const T*)pwv; const T* pb = (const T*)pbv;
    const T* mw = (const T*)mwv; const T* mb = (const T*)mbv;
    int h = threadIdx.x;
    int r0 = blockIdx.x * 4;
    __shared__ float gl[4][Dn];
    __shared__ float yl[4][Dn];
    for (int r = 0; r < 4; ++r) gl[r][h] = G[(r0 + r) * Dn + h];
    __syncthreads();
    float acc[4] = {0,0,0,0};
    for (int k = 0; k < Dn; ++k) {
        float w = cvt(pw[k * Dn + h]);
#pragma unroll
        for (int r = 0; r < 4; ++r) acc[r] += gl[r][k] * w;
    }
    float bp = cvt(pb[h]);
    for (int r = 0; r < 4; ++r) yl[r][h] = acc[r] + bp;
    __syncthreads();
    float a2[4] = {0,0,0,0};
    for (int k = 0; k < Dn; ++k) {
        float w = cvt(mw[k * Dn + h]);
#pragma unroll
        for (int r = 0; r < 4; ++r) a2[r] += yl[r][k] * w;
    }
    float bm = cvt(mb[h]);
    for (int r = 0; r < 4; ++r) mh_raw[(r0 + r) * Dn + h] = a2[r] + bm;
}

__global__ void k_pmhc(const float* G, const void* pw, const void* pb,
                       const void* mw, const void* mb, float* mh_raw, const void* alpha) {
    if (is_bf16(alpha)) pmhc_body<bf16>(G, pw, pb, mw, mb, mh_raw);
    else                pmhc_body<float>(G, pw, pb, mw, mb, mh_raw);
}

// ---------------------------------------------------------------------------
// Generic per-(b,d) column stats over an f32 (B,N,D) buffer, folding affine
// params into scale/shift. Wave-per-column, grid = 64 x 256.
template <typename T>
__device__ void colstats_body(const float* __restrict__ src, const void* wv, const void* bv,
                              float* __restrict__ sc, float* __restrict__ sh) {
    const T* w = (const T*)wv; const T* bb = (const T*)bv;
    int wave = threadIdx.x >> 6, lane = threadIdx.x & 63;
    int c = blockIdx.x * 4 + wave;   // 0..255
    int b = c >> 7, d = c & 127;
    const float* p = src + (size_t)b * Nn * Dn + d;
    float s = 0.f, ss = 0.f;
#pragma unroll
    for (int k = 0; k < 8; ++k) {
        float x = p[(size_t)(lane + 64 * k) * Dn];
        s += x; ss += x * x;
    }
#pragma unroll
    for (int off = 32; off > 0; off >>= 1) {
        s += __shfl_down(s, off);
        ss += __shfl_down(ss, off);
    }
    if (lane == 0) {
        float m = s * (1.f / Nn);
        float v = fmaxf(ss * (1.f / Nn) - m * m, 0.f);
        float rstd = rsqrtf(v + 1e-5f);
        float scale = rstd * cvt(w[d]);
        sc[c] = scale;
        sh[c] = cvt(bb[d]) - m * scale;
    }
}

__global__ void k_colstats(const float* src, const void* w, const void* b,
                           float* sc, float* sh, const void* alpha) {
    if (is_bf16(alpha)) colstats_body<bf16>(src, w, b, sc, sh);
    else                colstats_body<float>(src, w, b, sc, sh);
}

// ---------------------------------------------------------------------------
// t = rn + inorm(mh_raw, n3), elementwise; rn reconstructed from raw row + stats.
// grid = 256 x 256.
template <typename T>
__device__ void buildx_body(const void* rowv, const float* __restrict__ st,
                            const float* __restrict__ mh, float* __restrict__ t) {
    const T* row = (const T*)rowv;
    for (int e = blockIdx.x * 256 + threadIdx.x; e < BND; e += 256 * 256) {
        int d = e & 127;
        int b = e >> 16;
        int c = b * 128 + d;
        float rn = cvt(row[e]) * st[ST_IN_SC + c] + st[ST_IN_SH + c];
        float mhn = mh[e] * st[ST_MH_SC + c] + st[ST_MH_SH + c];
        t[e] = rn + mhn;
    }
}

__global__ void k_buildx(const void* row, const float* st, const float* mh, float* t,
                         const void* alpha) {
    if (is_bf16(alpha)) buildx_body<bf16>(row, st, mh, t);
    else                buildx_body<float>(row, st, mh, t);
}

// ---------------------------------------------------------------------------
// FFN: x = normalize(t) inline; outpre = x + relu(x@w1+b1)@w2+b2.
// 4 rows/block, 512 threads; pass2 split 4-way over hidden with LDS reduce.
template <typename T>
__device__ void ffn_body(const float* __restrict__ t, const float* __restrict__ st,
                         const void* w1v, const void* b1v,
                         const void* w2v, const void* b2v, float* outpre) {
    const T* w1 = (const T*)w1v; const T* bb1p = (const T*)b1v;
    const T* w2 = (const T*)w2v; const T* bb2p = (const T*)b2v;
    int tid = threadIdx.x;
    int r0 = blockIdx.x * 4;
    int b = r0 >> 9;
    __shared__ float xl[4][Dn];
    __shared__ float hl[4][FHn];
    __shared__ float red[4][4][Dn];
    {
        int r = tid >> 7, d = tid & 127;
        int c = b * 128 + d;
        xl[r][d] = t[(r0 + r) * Dn + d] * st[ST_X_SC + c] + st[ST_X_SH + c];
    }
    __syncthreads();
    float acc[4] = {0,0,0,0};
    for (int k = 0; k < Dn; ++k) {
        float w = cvt(w1[k * FHn + tid]);
#pragma unroll
        for (int r = 0; r < 4; ++r) acc[r] += xl[r][k] * w;
    }
    float bb1 = cvt(bb1p[tid]);
    for (int r = 0; r < 4; ++r) hl[r][tid] = fmaxf(acc[r] + bb1, 0.f);
    __syncthreads();
    {
        int d = tid & 127, grp = tid >> 7;
        float a2[4] = {0,0,0,0};
        int k0 = grp * 128;
        for (int k = k0; k < k0 + 128; ++k) {
            float w = cvt(w2[k * Dn + d]);
#pragma unroll
            for (int r = 0; r < 4; ++r) a2[r] += hl[r][k] * w;
        }
#pragma unroll
        for (int r = 0; r < 4; ++r) red[grp][r][d] = a2[r];
    }
    __syncthreads();
    if (tid < Dn) {
        float bb2 = cvt(bb2p[tid]);
#pragma unroll
        for (int r = 0; r < 4; ++r) {
            float sum = red[0][r][tid] + red[1][r][tid] + red[2][r][tid] + red[3][r][tid];
            outpre[(r0 + r) * Dn + tid] = xl[r][tid] + sum + bb2;
        }
    }
}

__global__ void k_ffn(const float* t, const float* st, const void* w1, const void* b1,
                      const void* w2, const void* b2, float* outpre, const void* alpha) {
    if (is_bf16(alpha)) ffn_body<bf16>(t, st, w1, b1, w2, b2, outpre);
    else                ffn_body<float>(t, st, w1, b1, w2, b2, outpre);
}

// ---------------------------------------------------------------------------
// out = outpre*scO + shO, cast to I/O dtype. grid = 256 x 256.
template <typename T>
__device__ void out_body(const float* __restrict__ outpre, const float* __restrict__ st,
                         void* outv) {
    T* out = (T*)outv;
    for (int e = blockIdx.x * 256 + threadIdx.x; e < BND; e += 256 * 256) {
        int d = e & 127;
        int b = e >> 16;
        int c = b * 128 + d;
        out[e] = (T)(outpre[e] * st[ST_O_SC + c] + st[ST_O_SH + c]);
    }
}

__global__ void k_out(const float* outpre, const float* st, void* out, const void* alpha) {
    if (is_bf16(alpha)) out_body<bf16>(outpre, st, out);
    else                out_body<float>(outpre, st, out);
}

// ---------------------------------------------------------------------------
extern "C" void kernel_launch(void* const* d_in, const int* in_sizes, int n_in,
                              void* d_out, int out_size, void* d_ws, size_t ws_size,
                              hipStream_t stream) {
    const void* row_emb  = d_in[0];
    const void* col_emb  = d_in[1];
    const void* cost_mat = d_in[2];
    const void* coords   = d_in[3];
    const void* alpha    = d_in[4];
    const void* n1w = d_in[5];  const void* n1b = d_in[6];
    const void* n2w = d_in[7];  const void* n2b = d_in[8];
    const void* n3w = d_in[9];  const void* n3b = d_in[10];
    const void* f1w = d_in[11]; const void* f1b = d_in[12];
    const void* f2w = d_in[13]; const void* f2b = d_in[14];
    const void* qw = d_in[15];  const void* qb = d_in[16];
    const void* kw = d_in[17];  const void* kb = d_in[18];
    const void* vw = d_in[19];  const void* vb = d_in[20];
    const void* pw = d_in[21];  const void* pb = d_in[22];
    const void* mw = d_in[23];  const void* mb = d_in[24];
    const void* dw1 = d_in[25]; const void* db1 = d_in[26];
    const void* dw2 = d_in[27]; const void* db2 = d_in[28];
    const void* aw1 = d_in[29]; const void* ab1 = d_in[30];
    const void* aw2 = d_in[31]; const void* ab2 = d_in[32];
    const void* gw = d_in[33];  const void* gb = d_in[34];
    const void* ow = d_in[35];  const void* ob = d_in[36];
    const void* ffw1 = d_in[37]; const void* ffb1 = d_in[38];
    const void* ffw2 = d_in[39]; const void* ffb2 = d_in[40];

    float* ws = (float*)d_ws;
    float* Q    = ws + WS_Q;
    float* Kraw = ws + WS_K;
    float* V    = ws + WS_V;
    float* eK   = ws + WS_EK;
    float* eKV  = ws + WS_EKV;
    float* eab  = ws + WS_EAB;
    float* st   = ws + WS_ST;

    float* G      = Kraw;       // Kraw dead after k_kekv
    float* mh     = V;          // V dead after k_kekv
    float* tbuf   = Q;          // Q dead after k_numden
    float* outpre = eK;         // eK dead after k_numden

    k_head<<<129, 256, 0, stream>>>(row_emb, col_emb, n1w, n1b, n2w, n2b,
                                    dw1, db1, dw2, db2, aw1, ab1, aw2, ab2,
                                    gw, gb, ow, ob, alpha, st);
    k_qkv<<<(Bn * Nn) / 4, 128, 0, stream>>>(row_emb, col_emb, st, qw, qb, kw, kb, vw, vb,
                                             Q, Kraw, V, alpha);
    k_kekv<<<64, 256, 0, stream>>>(Kraw, V, eK, eKV, st);
    k_eab<<<Bn * Nn, 256, 0, stream>>>(cost_mat, coords, st + ST_PRE, eab, alpha);
    k_numden<<<(Bn * Nn) / 4, 128, 0, stream>>>(eab, eK, eKV, Q, G);
    k_pmhc<<<(Bn * Nn) / 4, 128, 0, stream>>>(G, pw, pb, mw, mb, mh, alpha);
    k_colstats<<<64, 256, 0, stream>>>(mh, n3w, n3b, st + ST_MH_SC, st + ST_MH_SH, alpha);
    k_buildx<<<256, 256, 0, stream>>>(row_emb, st, mh, tbuf, alpha);
    k_colstats<<<64, 256, 0, stream>>>(tbuf, f1w, f1b, st + ST_X_SC, st + ST_X_SH, alpha);
    k_ffn<<<(Bn * Nn) / 4, 512, 0, stream>>>(tbuf, st, ffw1, ffb1, ffw2, ffb2, outpre, alpha);
    k_colstats<<<64, 256, 0, stream>>>(outpre, f2w, f2b, st + ST_O_SC, st + ST_O_SH, alpha);
    k_out<<<256, 256, 0, stream>>>(outpre, st, d_out, alpha);
}

// Round 4
// 269.310 us; speedup vs baseline: 1.5527x; 1.1300x over previous
//
#include <hip/hip_runtime.h>
#include <hip/hip_bf16.h>
#include <math.h>

// Problem constants
#define Bn  2
#define Nn  512
#define Dn  128
#define FHn 512
#define BND (Bn*Nn*Dn)   // 131072

typedef __hip_bfloat16 bf16;

__device__ __forceinline__ float cvt(float x) { return x; }
__device__ __forceinline__ float cvt(bf16 x) { return __bfloat162float(x); }
__device__ __forceinline__ float sigmoidf_(float x) { return 1.0f / (1.0f + expf(-x)); }
// dtype flag: alpha == 1.0 exactly. bf16 stores 0x3F80 in bytes[0:2); f32 stores 0x0000.
__device__ __forceinline__ bool is_bf16(const void* alpha) {
    return ((const unsigned short*)alpha)[0] == 0x3F80;
}

// ---------------------------------------------------------------------------
// Workspace layout (float offsets). S = one (B,N,D) f32 slab = 131072 floats.
#define S_ 131072
#define WS_Q    (0 * S_)   // reused: t (buildx output)
#define WS_K    (1 * S_)   // reused: G
#define WS_V    (2 * S_)   // reused: mh_raw
#define WS_EK   (3 * S_)   // reused: outpre
#define WS_EKV  (4 * S_)
#define WS_EAB  (5 * S_)   // (B,N,N) f32 = 4 slabs
#define WS_ST   (9 * S_)   // stats + pre region

// stats region (float offsets inside WS_ST)
#define ST_IN_SC   0      // 512: [which*256 + b*128 + d]
#define ST_IN_SH   512
#define ST_MH_SC   1536
#define ST_MH_SH   1792
#define ST_X_SC    2048
#define ST_X_SH    2304
#define ST_O_SC    2560
#define ST_O_SH    2816
#define ST_PRE     3072   // 1040 floats

// pre[] layout (relative to ST_PRE)
#define P_W1   0
#define P_B1   128
#define P_A1   256
#define P_AB1  384
#define P_UD   512
#define P_VD   640
#define P_UA   768
#define P_VA   896
#define P_SC   1024  // cds, cdt, cas, cat, gate_b, outlin_b, alpha

// ---------------------------------------------------------------------------
// k_head: blocks 0..127 = input instance-norm stats (512 columns, wave-per-col);
// block 128 = pre-fold of the DistAngleFusion MLPs.
template <typename T>
__device__ void head_stats(const void* rowv, const void* colv,
                           const void* n1wv, const void* n1bv,
                           const void* n2wv, const void* n2bv, float* st) {
    int wave = threadIdx.x >> 6, lane = threadIdx.x & 63;
    int cid = blockIdx.x * 4 + wave;          // 0..511
    int which = cid >> 8, rem = cid & 255;
    int b = rem >> 7, d = rem & 127;
    const T* src = (which ? (const T*)colv : (const T*)rowv) + (size_t)b * Nn * Dn + d;
    float s = 0.f, ss = 0.f;
#pragma unroll
    for (int k = 0; k < 8; ++k) {
        float x = cvt(src[(size_t)(lane + 64 * k) * Dn]);
        s += x; ss += x * x;
    }
#pragma unroll
    for (int off = 32; off > 0; off >>= 1) {
        s += __shfl_down(s, off);
        ss += __shfl_down(ss, off);
    }
    if (lane == 0) {
        float m = s * (1.f / Nn);
        float v = fmaxf(ss * (1.f / Nn) - m * m, 0.f);
        float rstd = rsqrtf(v + 1e-5f);
        const T* w = which ? (const T*)n2wv : (const T*)n1wv;
        const T* bb = which ? (const T*)n2bv : (const T*)n1bv;
        float sc = rstd * cvt(w[d]);
        st[ST_IN_SC + cid] = sc;
        st[ST_IN_SH + cid] = cvt(bb[d]) - m * sc;
    }
}

template <typename T>
__device__ void pre_fold(const void* dw1v, const void* db1v, const void* dw2v, const void* db2v,
                         const void* aw1v, const void* ab1v, const void* aw2v, const void* ab2v,
                         const void* gwv, const void* gbv, const void* owv, const void* obv,
                         const void* alphav, float* pre) {
    const T* dw1 = (const T*)dw1v; const T* db1 = (const T*)db1v;
    const T* dw2 = (const T*)dw2v; const T* db2 = (const T*)db2v;
    const T* aw1 = (const T*)aw1v; const T* ab1 = (const T*)ab1v;
    const T* aw2 = (const T*)aw2v; const T* ab2 = (const T*)ab2v;
    const T* gw = (const T*)gwv;   const T* gb = (const T*)gbv;
    const T* ow = (const T*)owv;   const T* ob = (const T*)obv;
    const T* alpha = (const T*)alphav;
    int k = threadIdx.x;
    if (k >= 128) return;
    float ud = 0.f, vd = 0.f, ua = 0.f, va = 0.f;
#pragma unroll 4
    for (int d = 0; d < Dn; ++d) {
        float w2 = cvt(dw2[k * Dn + d]);
        float a2 = cvt(aw2[k * Dn + d]);
        float o = cvt(ow[d]);
        ud += w2 * o;
        vd += w2 * cvt(gw[d]);
        ua += a2 * o;
        va += a2 * cvt(gw[Dn + d]);
    }
    pre[P_W1 + k]  = cvt(dw1[k]);
    pre[P_B1 + k]  = cvt(db1[k]);
    pre[P_A1 + k]  = cvt(aw1[k]);
    pre[P_AB1 + k] = cvt(ab1[k]);
    pre[P_UD + k] = ud;
    pre[P_VD + k] = vd;
    pre[P_UA + k] = ua;
    pre[P_VA + k] = va;
    if (k == 0) {
        float cds = 0.f, cdt = 0.f, cas = 0.f, cat = 0.f;
        for (int d = 0; d < Dn; ++d) {
            float o = cvt(ow[d]);
            cds += cvt(db2[d]) * o;
            cdt += cvt(db2[d]) * cvt(gw[d]);
            cas += cvt(ab2[d]) * o;
            cat += cvt(ab2[d]) * cvt(gw[Dn + d]);
        }
        pre[P_SC + 0] = cds;
        pre[P_SC + 1] = cdt;
        pre[P_SC + 2] = cas;
        pre[P_SC + 3] = cat;
        pre[P_SC + 4] = cvt(gb[0]);
        pre[P_SC + 5] = cvt(ob[0]);
        pre[P_SC + 6] = cvt(alpha[0]);
    }
}

__global__ void k_head(const void* row, const void* col,
                       const void* n1w, const void* n1b, const void* n2w, const void* n2b,
                       const void* dw1, const void* db1, const void* dw2, const void* db2,
                       const void* aw1, const void* ab1, const void* aw2, const void* ab2,
                       const void* gw, const void* gb, const void* ow, const void* ob,
                       const void* alpha, float* st) {
    bool bf = is_bf16(alpha);
    if (blockIdx.x < 128) {
        if (bf) head_stats<bf16>(row, col, n1w, n1b, n2w, n2b, st);
        else    head_stats<float>(row, col, n1w, n1b, n2w, n2b, st);
    } else {
        if (bf) pre_fold<bf16>(dw1, db1, dw2, db2, aw1, ab1, aw2, ab2, gw, gb, ow, ob, alpha, st + ST_PRE);
        else    pre_fold<float>(dw1, db1, dw2, db2, aw1, ab1, aw2, ab2, gw, gb, ow, ob, alpha, st + ST_PRE);
    }
}

// ---------------------------------------------------------------------------
// k_qkv: 4 rows/block, 256 threads (h = tid&127, half = tid>>7 splits K-range),
// 256 blocks. Inline input normalization via stats; LDS reduce of halves.
template <typename T>
__device__ void qkv_body(const void* rowv, const void* colv, const float* __restrict__ st,
                         const void* qwv, const void* qbv, const void* kwv, const void* kbv,
                         const void* vwv, const void* vbv,
                         float* Q, float* Kraw, float* V) {
    const T* row = (const T*)rowv; const T* col = (const T*)colv;
    const T* qw = (const T*)qwv; const T* qb = (const T*)qbv;
    const T* kw = (const T*)kwv; const T* kb = (const T*)kbv;
    const T* vw = (const T*)vwv; const T* vb = (const T*)vbv;
    int tid = threadIdx.x;
    int h = tid & 127, half = tid >> 7;
    int r0 = blockIdx.x * 4;
    int b = r0 >> 9;
    __shared__ float lr[4][Dn], lc[4][Dn];
    __shared__ float redq[2][4][Dn], redk[2][4][Dn], redv[2][4][Dn];
    {
        // 256 threads load 4x128 rows of each (2 elems per thread)
        for (int e = tid; e < 4 * Dn; e += 256) {
            int r = e >> 7, d = e & 127;
            float scR = st[ST_IN_SC + b * 128 + d],       shR = st[ST_IN_SH + b * 128 + d];
            float scC = st[ST_IN_SC + 256 + b * 128 + d], shC = st[ST_IN_SH + 256 + b * 128 + d];
            lr[r][d] = cvt(row[(size_t)(r0 + r) * Dn + d]) * scR + shR;
            lc[r][d] = cvt(col[(size_t)(r0 + r) * Dn + d]) * scC + shC;
        }
    }
    __syncthreads();
    float q[4] = {0,0,0,0}, kk[4] = {0,0,0,0}, vv[4] = {0,0,0,0};
    int k0 = half * 64;
#pragma unroll 8
    for (int k = k0; k < k0 + 64; ++k) {
        float wq = cvt(qw[k * Dn + h]);
        float wk = cvt(kw[k * Dn + h]);
        float wv = cvt(vw[k * Dn + h]);
#pragma unroll
        for (int r = 0; r < 4; ++r) {
            q[r] += lr[r][k] * wq;
            kk[r] += lc[r][k] * wk;
            vv[r] += lc[r][k] * wv;
        }
    }
#pragma unroll
    for (int r = 0; r < 4; ++r) {
        redq[half][r][h] = q[r];
        redk[half][r][h] = kk[r];
        redv[half][r][h] = vv[r];
    }
    __syncthreads();
    if (tid < 128) {
        float bq = cvt(qb[h]), bk = cvt(kb[h]), bv = cvt(vb[h]);
#pragma unroll
        for (int r = 0; r < 4; ++r) {
            Q[(r0 + r) * Dn + h] = sigmoidf_(redq[0][r][h] + redq[1][r][h] + bq);
            Kraw[(r0 + r) * Dn + h] = redk[0][r][h] + redk[1][r][h] + bk;
            V[(r0 + r) * Dn + h] = redv[0][r][h] + redv[1][r][h] + bv;
        }
    }
}

__global__ void k_qkv(const void* row, const void* col, const float* st,
                      const void* qw, const void* qb, const void* kw, const void* kb,
                      const void* vw, const void* vb,
                      float* Q, float* Kraw, float* V, const void* alpha) {
    if (is_bf16(alpha)) qkv_body<bf16>(row, col, st, qw, qb, kw, kb, vw, vb, Q, Kraw, V);
    else                qkv_body<float>(row, col, st, qw, qb, kw, kb, vw, vb, Q, Kraw, V);
}

// ---------------------------------------------------------------------------
// k_kekv: per-(b,h) K-softmax + fused eK/eKV write. Wave-per-column, 64 x 256.
__global__ void k_kekv(const float* __restrict__ Kraw, const float* __restrict__ V,
                       float* __restrict__ eK, float* __restrict__ eKV) {
    int wave = threadIdx.x >> 6, lane = threadIdx.x & 63;
    int c = blockIdx.x * 4 + wave;   // 0..255
    int b = c >> 7, h = c & 127;
    const float* kb = Kraw + (size_t)b * Nn * Dn + h;
    const float* vb = V + (size_t)b * Nn * Dn + h;
    float* ekb = eK + (size_t)b * Nn * Dn + h;
    float* evb = eKV + (size_t)b * Nn * Dn + h;
    float x[8];
    float mx = -1e30f;
#pragma unroll
    for (int k = 0; k < 8; ++k) {
        x[k] = kb[(size_t)(lane + 64 * k) * Dn];
        mx = fmaxf(mx, x[k]);
    }
#pragma unroll
    for (int off = 32; off > 0; off >>= 1) mx = fmaxf(mx, __shfl_xor(mx, off));
    float s = 0.f;
#pragma unroll
    for (int k = 0; k < 8; ++k) s += expf(x[k] - mx);
#pragma unroll
    for (int off = 32; off > 0; off >>= 1) s += __shfl_xor(s, off);
    float rs = 1.f / s;
#pragma unroll
    for (int k = 0; k < 8; ++k) {
        size_t a = (size_t)(lane + 64 * k) * Dn;
        float ek = expf(expf(x[k] - mx) * rs);
        ekb[a] = ek;
        evb[a] = ek * vb[a];
    }
}

// ---------------------------------------------------------------------------
// adapt_bias row -> softmax over j -> exp -> eab.  grid = B*N, 256 threads.
template <typename T>
__device__ void eab_body(const void* costv, const void* coordsv,
                         const float* __restrict__ pre, float* __restrict__ eab) {
    const T* cost = (const T*)costv;
    const T* coords = (const T*)coordsv;
    int bi = blockIdx.x;
    int b = bi >> 9, i = bi & 511;
    int t = threadIdx.x;
    __shared__ float abv[Nn];
    __shared__ float red[256];
    const float* pw1 = pre + P_W1;
    const float* pb1 = pre + P_B1;
    const float* pa1 = pre + P_A1;
    const float* pab = pre + P_AB1;
    const float* pud = pre + P_UD;
    const float* pvd = pre + P_VD;
    const float* pua = pre + P_UA;
    const float* pva = pre + P_VA;
    float cds = pre[P_SC+0], cdt = pre[P_SC+1], cas = pre[P_SC+2], cat = pre[P_SC+3];
    float gbias = pre[P_SC+4], obias = pre[P_SC+5], alpha = pre[P_SC+6];
    float cix = cvt(coords[((size_t)b * Nn + i) * 2 + 0]);
    float ciy = cvt(coords[((size_t)b * Nn + i) * 2 + 1]);
    const T* crow = cost + (size_t)b * Nn * Nn + (size_t)i * Nn;

    for (int j = t; j < Nn; j += 256) {
        float c = cvt(crow[j]);
        float dx = cix - cvt(coords[((size_t)b * Nn + j) * 2 + 0]);
        float dy = ciy - cvt(coords[((size_t)b * Nn + j) * 2 + 1]);
        float ang = (dx == 0.f && dy == 0.f) ? 0.f : atan2f(dy, dx);
        float sd = cds, td = cdt, sa = cas, ta = cat;
#pragma unroll 4
        for (int k = 0; k < Dn; ++k) {
            float r = fmaxf(fmaf(c, pw1[k], pb1[k]), 0.f);
            sd = fmaf(r, pud[k], sd);
            td = fmaf(r, pvd[k], td);
            float ra = fmaxf(fmaf(ang, pa1[k], pab[k]), 0.f);
            sa = fmaf(ra, pua[k], sa);
            ta = fmaf(ra, pva[k], ta);
        }
        float gv = sigmoidf_(td + ta + gbias);
        abv[j] = alpha * (gv * sd + (1.f - gv) * sa + obias);
    }
    __syncthreads();
    float m = fmaxf(abv[t], abv[t + 256]);
    red[t] = m; __syncthreads();
    for (int s = 128; s > 0; s >>= 1) {
        if (t < s) red[t] = fmaxf(red[t], red[t + s]);
        __syncthreads();
    }
    m = red[0];
    __syncthreads();
    float e0 = expf(abv[t] - m), e1 = expf(abv[t + 256] - m);
    red[t] = e0 + e1; __syncthreads();
    for (int s = 128; s > 0; s >>= 1) {
        if (t < s) red[t] += red[t + s];
        __syncthreads();
    }
    float rsum = 1.f / red[0];
    float* orow = eab + (size_t)bi * Nn;
    orow[t] = expf(e0 * rsum);
    orow[t + 256] = expf(e1 * rsum);
}

__global__ void k_eab(const void* cost, const void* coords,
                      const float* pre, float* eab, const void* alpha) {
    if (is_bf16(alpha)) eab_body<bf16>(cost, coords, pre, eab);
    else                eab_body<float>(cost, coords, pre, eab);
}

// ---------------------------------------------------------------------------
// num/den einsums + G = Q*num/den. 4 rows/block, 256 threads (halves over j),
// 256 blocks.
__global__ void k_numden(const float* __restrict__ eab, const float* __restrict__ eK,
                         const float* __restrict__ eKV, const float* __restrict__ Q,
                         float* __restrict__ G) {
    int tid = threadIdx.x;
    int h = tid & 127, half = tid >> 7;
    int r0 = blockIdx.x * 4;
    int b = r0 >> 9;
    __shared__ float ab[4][Nn];
    __shared__ float redn[2][4][Dn], redd[2][4][Dn];
    for (int e = tid; e < 4 * Nn; e += 256) {
        int r = e >> 9, j = e & 511;
        ab[r][j] = eab[(size_t)(r0 + r) * Nn + j];
    }
    __syncthreads();
    const float* ekb = eK + (size_t)b * Nn * Dn;
    const float* evb = eKV + (size_t)b * Nn * Dn;
    float num[4] = {0,0,0,0}, den[4] = {0,0,0,0};
    int j0 = half * 256;
#pragma unroll 4
    for (int j = j0; j < j0 + 256; ++j) {
        float ek = ekb[(size_t)j * Dn + h];
        float ev = evb[(size_t)j * Dn + h];
#pragma unroll
        for (int r = 0; r < 4; ++r) {
            num[r] += ab[r][j] * ev;
            den[r] += ab[r][j] * ek;
        }
    }
#pragma unroll
    for (int r = 0; r < 4; ++r) { redn[half][r][h] = num[r]; redd[half][r][h] = den[r]; }
    __syncthreads();
    if (tid < 128) {
#pragma unroll
        for (int r = 0; r < 4; ++r) {
            int row = r0 + r;
            float nu = redn[0][r][h] + redn[1][r][h];
            float de = redd[0][r][h] + redd[1][r][h];
            G[row * Dn + h] = Q[row * Dn + h] * nu / de;
        }
    }
}

// ---------------------------------------------------------------------------
// Yt = G@pw+pb then mh_raw = Yt@mw+mb. 4 rows/block, 256 threads (halves),
// 256 blocks.
template <typename T>
__device__ void pmhc_body(const float* __restrict__ G, const void* pwv, const void* pbv,
                          const void* mwv, const void* mbv, float* mh_raw) {
    const T* pw = (const T*)pwv; const T* pb = (const T*)pbv;
    const T* mw = (const T*)mwv; const T* mb = (const T*)mbv;
    int tid = threadIdx.x;
    int h = tid & 127, half = tid >> 7;
    int r0 = blockIdx.x * 4;
    __shared__ float gl[4][Dn];
    __shared__ float yl[4][Dn];
    __shared__ float red[2][4][Dn];
    for (int e = tid; e < 4 * Dn; e += 256) {
        int r = e >> 7, d = e & 127;
        gl[r][d] = G[(r0 + r) * Dn + d];
    }
    __syncthreads();
    {
        float acc[4] = {0,0,0,0};
        int k0 = half * 64;
#pragma unroll 8
        for (int k = k0; k < k0 + 64; ++k) {
            float w = cvt(pw[k * Dn + h]);
#pragma unroll
            for (int r = 0; r < 4; ++r) acc[r] += gl[r][k] * w;
        }
#pragma unroll
        for (int r = 0; r < 4; ++r) red[half][r][h] = acc[r];
    }
    __syncthreads();
    if (tid < 128) {
        float bp = cvt(pb[h]);
#pragma unroll
        for (int r = 0; r < 4; ++r) yl[r][h] = red[0][r][h] + red[1][r][h] + bp;
    }
    __syncthreads();
    {
        float acc[4] = {0,0,0,0};
        int k0 = half * 64;
#pragma unroll 8
        for (int k = k0; k < k0 + 64; ++k) {
            float w = cvt(mw[k * Dn + h]);
#pragma unroll
            for (int r = 0; r < 4; ++r) acc[r] += yl[r][k] * w;
        }
#pragma unroll
        for (int r = 0; r < 4; ++r) red[half][r][h] = acc[r];
    }
    __syncthreads();
    if (tid < 128) {
        float bm = cvt(mb[h]);
#pragma unroll
        for (int r = 0; r < 4; ++r)
            mh_raw[(r0 + r) * Dn + h] = red[0][r][h] + red[1][r][h] + bm;
    }
}

__global__ void k_pmhc(const float* G, const void* pw, const void* pb,
                       const void* mw, const void* mb, float* mh_raw, const void* alpha) {
    if (is_bf16(alpha)) pmhc_body<bf16>(G, pw, pb, mw, mb, mh_raw);
    else                pmhc_body<float>(G, pw, pb, mw, mb, mh_raw);
}

// ---------------------------------------------------------------------------
// Generic per-(b,d) column stats over an f32 (B,N,D) buffer, folding affine
// params into scale/shift. Wave-per-column, grid = 64 x 256.
template <typename T>
__device__ void colstats_body(const float* __restrict__ src, const void* wv, const void* bv,
                              float* __restrict__ sc, float* __restrict__ sh) {
    const T* w = (const T*)wv; const T* bb = (const T*)bv;
    int wave = threadIdx.x >> 6, lane = threadIdx.x & 63;
    int c = blockIdx.x * 4 + wave;   // 0..255
    int b = c >> 7, d = c & 127;
    const float* p = src + (size_t)b * Nn * Dn + d;
    float s = 0.f, ss = 0.f;
#pragma unroll
    for (int k = 0; k < 8; ++k) {
        float x = p[(size_t)(lane + 64 * k) * Dn];
        s += x; ss += x * x;
    }
#pragma unroll
    for (int off = 32; off > 0; off >>= 1) {
        s += __shfl_down(s, off);
        ss += __shfl_down(ss, off);
    }
    if (lane == 0) {
        float m = s * (1.f / Nn);
        float v = fmaxf(ss * (1.f / Nn) - m * m, 0.f);
        float rstd = rsqrtf(v + 1e-5f);
        float scale = rstd * cvt(w[d]);
        sc[c] = scale;
        sh[c] = cvt(bb[d]) - m * scale;
    }
}

__global__ void k_colstats(const float* src, const void* w, const void* b,
                           float* sc, float* sh, const void* alpha) {
    if (is_bf16(alpha)) colstats_body<bf16>(src, w, b, sc, sh);
    else                colstats_body<float>(src, w, b, sc, sh);
}

// ---------------------------------------------------------------------------
// Fused: t = rn + inorm(mh,n3) (write t) AND column stats of t folded with
// fn1 -> ST_X. Wave-per-column, grid = 64 x 256.
template <typename T>
__device__ void buildx_body(const void* rowv, float* __restrict__ st,
                            const float* __restrict__ mh, float* __restrict__ t,
                            const void* f1wv, const void* f1bv) {
    const T* row = (const T*)rowv;
    const T* f1w = (const T*)f1wv; const T* f1b = (const T*)f1bv;
    int wave = threadIdx.x >> 6, lane = threadIdx.x & 63;
    int c = blockIdx.x * 4 + wave;   // 0..255
    int b = c >> 7, d = c & 127;
    float scI = st[ST_IN_SC + c], shI = st[ST_IN_SH + c];
    float scM = st[ST_MH_SC + c], shM = st[ST_MH_SH + c];
    const T* rp = row + (size_t)b * Nn * Dn + d;
    const float* mp = mh + (size_t)b * Nn * Dn + d;
    float* tp = t + (size_t)b * Nn * Dn + d;
    float s = 0.f, ss = 0.f;
#pragma unroll
    for (int k = 0; k < 8; ++k) {
        size_t a = (size_t)(lane + 64 * k) * Dn;
        float x = cvt(rp[a]) * scI + shI + mp[a] * scM + shM;
        tp[a] = x;
        s += x; ss += x * x;
    }
#pragma unroll
    for (int off = 32; off > 0; off >>= 1) {
        s += __shfl_down(s, off);
        ss += __shfl_down(ss, off);
    }
    if (lane == 0) {
        float m = s * (1.f / Nn);
        float v = fmaxf(ss * (1.f / Nn) - m * m, 0.f);
        float rstd = rsqrtf(v + 1e-5f);
        float scale = rstd * cvt(f1w[d]);
        st[ST_X_SC + c] = scale;
        st[ST_X_SH + c] = cvt(f1b[d]) - m * scale;
    }
}

__global__ void k_buildx(const void* row, float* st, const float* mh, float* t,
                         const void* f1w, const void* f1b, const void* alpha) {
    if (is_bf16(alpha)) buildx_body<bf16>(row, st, mh, t, f1w, f1b);
    else                buildx_body<float>(row, st, mh, t, f1w, f1b);
}

// ---------------------------------------------------------------------------
// FFN: x = normalize(t) inline; outpre = x + relu(x@w1+b1)@w2+b2.
// 4 rows/block, 256 threads, 256 blocks.
// pass1: thread owns hidden cols f=tid, tid+256 (8 accs).
// pass2: thread (d=tid&127, half=tid>>7) owns half the hidden range (4 accs).
template <typename T>
__device__ void ffn_body(const float* __restrict__ t, const float* __restrict__ st,
                         const void* w1v, const void* b1v,
                         const void* w2v, const void* b2v, float* outpre) {
    const T* w1 = (const T*)w1v; const T* bb1p = (const T*)b1v;
    const T* w2 = (const T*)w2v; const T* bb2p = (const T*)b2v;
    int tid = threadIdx.x;
    int r0 = blockIdx.x * 4;
    int b = r0 >> 9;
    __shared__ float xl[4][Dn];
    __shared__ float hl[4][FHn];
    __shared__ float red[2][4][Dn];
    for (int e = tid; e < 4 * Dn; e += 256) {
        int r = e >> 7, d = e & 127;
        int c = b * 128 + d;
        xl[r][d] = t[(r0 + r) * Dn + d] * st[ST_X_SC + c] + st[ST_X_SH + c];
    }
    __syncthreads();
    {
        float a0[4] = {0,0,0,0}, a1[4] = {0,0,0,0};
        int f0 = tid, f1 = tid + 256;
#pragma unroll 4
        for (int k = 0; k < Dn; ++k) {
            float w0 = cvt(w1[k * FHn + f0]);
            float w1v_ = cvt(w1[k * FHn + f1]);
#pragma unroll
            for (int r = 0; r < 4; ++r) {
                a0[r] += xl[r][k] * w0;
                a1[r] += xl[r][k] * w1v_;
            }
        }
        float bb0 = cvt(bb1p[f0]), bb1 = cvt(bb1p[f1]);
#pragma unroll
        for (int r = 0; r < 4; ++r) {
            hl[r][f0] = fmaxf(a0[r] + bb0, 0.f);
            hl[r][f1] = fmaxf(a1[r] + bb1, 0.f);
        }
    }
    __syncthreads();
    {
        int d = tid & 127, half = tid >> 7;
        float acc[4] = {0,0,0,0};
        int k0 = half * 256;
#pragma unroll 8
        for (int k = k0; k < k0 + 256; ++k) {
            float w = cvt(w2[k * Dn + d]);
#pragma unroll
            for (int r = 0; r < 4; ++r) acc[r] += hl[r][k] * w;
        }
#pragma unroll
        for (int r = 0; r < 4; ++r) red[half][r][d] = acc[r];
    }
    __syncthreads();
    if (tid < Dn) {
        float bb2 = cvt(bb2p[tid]);
#pragma unroll
        for (int r = 0; r < 4; ++r) {
            float sum = red[0][r][tid] + red[1][r][tid];
            outpre[(r0 + r) * Dn + tid] = xl[r][tid] + sum + bb2;
        }
    }
}

__global__ void k_ffn(const float* t, const float* st, const void* w1, const void* b1,
                      const void* w2, const void* b2, float* outpre, const void* alpha) {
    if (is_bf16(alpha)) ffn_body<bf16>(t, st, w1, b1, w2, b2, outpre);
    else                ffn_body<float>(t, st, w1, b1, w2, b2, outpre);
}

// ---------------------------------------------------------------------------
// out = outpre*scO + shO, cast to I/O dtype. grid = 256 x 256.
template <typename T>
__device__ void out_body(const float* __restrict__ outpre, const float* __restrict__ st,
                         void* outv) {
    T* out = (T*)outv;
    for (int e = blockIdx.x * 256 + threadIdx.x; e < BND; e += 256 * 256) {
        int d = e & 127;
        int b = e >> 16;
        int c = b * 128 + d;
        out[e] = (T)(outpre[e] * st[ST_O_SC + c] + st[ST_O_SH + c]);
    }
}

__global__ void k_out(const float* outpre, const float* st, void* out, const void* alpha) {
    if (is_bf16(alpha)) out_body<bf16>(outpre, st, out);
    else                out_body<float>(outpre, st, out);
}

// ---------------------------------------------------------------------------
extern "C" void kernel_launch(void* const* d_in, const int* in_sizes, int n_in,
                              void* d_out, int out_size, void* d_ws, size_t ws_size,
                              hipStream_t stream) {
    const void* row_emb  = d_in[0];
    const void* col_emb  = d_in[1];
    const void* cost_mat = d_in[2];
    const void* coords   = d_in[3];
    const void* alpha    = d_in[4];
    const void* n1w = d_in[5];  const void* n1b = d_in[6];
    const void* n2w = d_in[7];  const void* n2b = d_in[8];
    const void* n3w = d_in[9];  const void* n3b = d_in[10];
    const void* f1w = d_in[11]; const void* f1b = d_in[12];
    const void* f2w = d_in[13]; const void* f2b = d_in[14];
    const void* qw = d_in[15];  const void* qb = d_in[16];
    const void* kw = d_in[17];  const void* kb = d_in[18];
    const void* vw = d_in[19];  const void* vb = d_in[20];
    const void* pw = d_in[21];  const void* pb = d_in[22];
    const void* mw = d_in[23];  const void* mb = d_in[24];
    const void* dw1 = d_in[25]; const void* db1 = d_in[26];
    const void* dw2 = d_in[27]; const void* db2 = d_in[28];
    const void* aw1 = d_in[29]; const void* ab1 = d_in[30];
    const void* aw2 = d_in[31]; const void* ab2 = d_in[32];
    const void* gw = d_in[33];  const void* gb = d_in[34];
    const void* ow = d_in[35];  const void* ob = d_in[36];
    const void* ffw1 = d_in[37]; const void* ffb1 = d_in[38];
    const void* ffw2 = d_in[39]; const void* ffb2 = d_in[40];

    float* ws = (float*)d_ws;
    float* Q    = ws + WS_Q;
    float* Kraw = ws + WS_K;
    float* V    = ws + WS_V;
    float* eK   = ws + WS_EK;
    float* eKV  = ws + WS_EKV;
    float* eab  = ws + WS_EAB;
    float* st   = ws + WS_ST;

    float* G      = Kraw;       // Kraw dead after k_kekv
    float* mh     = V;          // V dead after k_kekv
    float* tbuf   = Q;          // Q dead after k_numden
    float* outpre = eK;         // eK dead after k_numden

    k_head<<<129, 256, 0, stream>>>(row_emb, col_emb, n1w, n1b, n2w, n2b,
                                    dw1, db1, dw2, db2, aw1, ab1, aw2, ab2,
                                    gw, gb, ow, ob, alpha, st);
    k_qkv<<<(Bn * Nn) / 4, 256, 0, stream>>>(row_emb, col_emb, st, qw, qb, kw, kb, vw, vb,
                                             Q, Kraw, V, alpha);
    k_kekv<<<64, 256, 0, stream>>>(Kraw, V, eK, eKV);
    k_eab<<<Bn * Nn, 256, 0, stream>>>(cost_mat, coords, st + ST_PRE, eab, alpha);
    k_numden<<<(Bn * Nn) / 4, 256, 0, stream>>>(eab, eK, eKV, Q, G);
    k_pmhc<<<(Bn * Nn) / 4, 256, 0, stream>>>(G, pw, pb, mw, mb, mh, alpha);
    k_colstats<<<64, 256, 0, stream>>>(mh, n3w, n3b, st + ST_MH_SC, st + ST_MH_SH, alpha);
    k_buildx<<<64, 256, 0, stream>>>(row_emb, st, mh, tbuf, f1w, f1b, alpha);
    k_ffn<<<(Bn * Nn) / 4, 256, 0, stream>>>(tbuf, st, ffw1, ffb1, ffw2, ffb2, outpre, alpha);
    k_colstats<<<64, 256, 0, stream>>>(outpre, f2w, f2b, st + ST_O_SC, st + ST_O_SH, alpha);
    k_out<<<256, 256, 0, stream>>>(outpre, st, d_out, alpha);
}